// Round 8
// baseline (437.675 us; speedup 1.0000x reference)
//
#include <hip/hip_runtime.h>
#include <hip/hip_fp16.h>

#define NFEAT 128

typedef _Float16 v8hf __attribute__((ext_vector_type(8)));
typedef float v4f __attribute__((ext_vector_type(4)));

// ---------------- degree histogram + per-edge rank (incl. self edges) --------
// Threads [0,E): real edges; [E,E+N): self edge n->n. deg then includes self,
// so dinv = rsqrt(deg) directly matches reference's deg+1.
__global__ void k_deg_rank(const int* __restrict__ dst, int* __restrict__ deg,
                           int* __restrict__ rank, int E, int N) {
  int e = blockIdx.x * blockDim.x + threadIdx.x;
  if (e < E) rank[e] = atomicAdd(&deg[dst[e]], 1);
  else if (e < E + N) rank[e] = atomicAdd(&deg[e - E], 1);
}

// ---------------- fill ssrc with sentinel N (pad slots gather zero row) ------
__global__ void k_fill(int* __restrict__ p, int v, int n) {
  int i = blockIdx.x * 256 + threadIdx.x;
  if (i < n) p[i] = v;
}

// ---------------- W transpose + fp16 cast: Wt[n][k] = half(W[k][n]) ----------
__global__ void k_prep_w(const float* __restrict__ W1, const float* __restrict__ W2,
                         _Float16* __restrict__ Wt1, _Float16* __restrict__ Wt2) {
  int idx = blockIdx.x * 256 + threadIdx.x;     // 0..32767
  const float* W = (idx < 16384) ? W1 : W2;
  _Float16* Wt = (idx < 16384) ? Wt1 : Wt2;
  int i = idx & 16383;
  int k = i >> 7, n = i & 127;
  Wt[n * 128 + k] = (_Float16)W[k * 128 + n];
}

// ---------------- 2-level exclusive scan over degrees padded to x16 ----------
__global__ __launch_bounds__(1024) void k_scan_blocks(const int* __restrict__ deg,
    int* __restrict__ base, int* __restrict__ partials, int n) {
  __shared__ int buf[1024];
  int tid = threadIdx.x;
  int i = blockIdx.x * 1024 + tid;
  int v = (i < n) ? ((deg[i] + 15) & ~15) : 0;
  buf[tid] = v;
  __syncthreads();
  #pragma unroll
  for (int off = 1; off < 1024; off <<= 1) {
    int t = (tid >= off) ? buf[tid - off] : 0;
    __syncthreads();
    buf[tid] += t;
    __syncthreads();
  }
  if (i <= n) base[i] = buf[tid] - v;
  if (tid == 1023) partials[blockIdx.x] = buf[tid];
}

__global__ void k_scan_partials(int* __restrict__ partials, int nb) {
  __shared__ int buf[128];
  int tid = threadIdx.x;
  int v = (tid < nb) ? partials[tid] : 0;
  buf[tid] = v;
  __syncthreads();
  #pragma unroll
  for (int off = 1; off < 128; off <<= 1) {
    int t = (tid >= off) ? buf[tid - off] : 0;
    __syncthreads();
    buf[tid] += t;
    __syncthreads();
  }
  if (tid < nb) partials[tid] = buf[tid] - v;
}

__global__ void k_finalize_base(int* __restrict__ base, const int* __restrict__ partials,
    const int* __restrict__ deg, float* __restrict__ dinv, int n) {
  int i = blockIdx.x * blockDim.x + threadIdx.x;
  if (i <= n) {
    base[i] += partials[i >> 10];
    if (i < n) dinv[i] = rsqrtf((float)deg[i]);   // deg already includes self
  }
}

__global__ void k_scatter(const int* __restrict__ src, const int* __restrict__ dst,
    const int* __restrict__ rank, const int* __restrict__ base,
    int* __restrict__ ssrc, int E, int N) {
  int e = blockIdx.x * blockDim.x + threadIdx.x;
  if (e < E) ssrc[base[dst[e]] + rank[e]] = src[e];
  else if (e < E + N) { int n = e - E; ssrc[base[n] + rank[e]] = n; }
}

// ---------------- zero sentinel row N of the sliced table --------------------
__global__ void k_zero_row(_Float16* __restrict__ g16, int N) {
  int i = threadIdx.x;           // 0..127
  int s = i >> 4, m = i & 15;
  g16[((size_t)s * (N + 1) + N) * 16 + m] = (_Float16)0.f;
}

// ---------------- MFMA fp16 GEMM: g16 = sliced( (A @ W) * dinv[row] ) ---------
// Slice stride is (N+1) rows (row N = zero sentinel).
template <typename AT>
__global__ __launch_bounds__(256) void k_gemm_mfma(
    const AT* __restrict__ A, const _Float16* __restrict__ Wt,
    const float* __restrict__ dinv, _Float16* __restrict__ g16, int N) {
  __shared__ _Float16 As[64][136];
  __shared__ _Float16 Ws[128][136];
  const int tid = threadIdx.x;
  const int row0 = blockIdx.x * 64;

  if constexpr (sizeof(AT) == 4) {   // fp32 input: load + cast
    #pragma unroll
    for (int i = 0; i < 8; i++) {
      int idx = tid + i * 256;       // 0..2047
      int row = idx >> 5;
      int c4 = idx & 31;
      int gr = row0 + row; gr = (gr < N) ? gr : (N - 1);
      float4 v = *(const float4*)((const float*)A + (size_t)gr * NFEAT + c4 * 4);
      _Float16* p = &As[row][c4 * 4];
      p[0] = (_Float16)v.x; p[1] = (_Float16)v.y;
      p[2] = (_Float16)v.z; p[3] = (_Float16)v.w;
    }
  } else {                           // fp16 input: straight copy
    #pragma unroll
    for (int i = 0; i < 4; i++) {
      int idx = tid + i * 256;
      int row = idx >> 4;
      int c8 = idx & 15;
      int gr = row0 + row; gr = (gr < N) ? gr : (N - 1);
      *(uint4*)&As[row][c8 * 8] =
          *(const uint4*)((const _Float16*)A + (size_t)gr * NFEAT + c8 * 8);
    }
  }
  #pragma unroll
  for (int i = 0; i < 8; i++) {
    int idx = tid + i * 256;
    int row = idx >> 4;
    int c8 = idx & 15;
    *(uint4*)&Ws[row][c8 * 8] = *(const uint4*)(Wt + (size_t)row * 128 + c8 * 8);
  }
  __syncthreads();

  const int wv = tid >> 6;
  const int lane = tid & 63;
  const int m = lane & 15;
  const int q = lane >> 4;

  v4f acc[8] = {};
  const _Float16* arow = &As[wv * 16 + m][0];
  #pragma unroll
  for (int kt = 0; kt < 4; kt++) {
    v8hf af = *(const v8hf*)(arow + kt * 32 + q * 8);
    #pragma unroll
    for (int ct = 0; ct < 8; ct++) {
      v8hf bf = *(const v8hf*)(&Ws[ct * 16 + m][kt * 32 + q * 8]);
      acc[ct] = __builtin_amdgcn_mfma_f32_16x16x32_f16(af, bf, acc[ct], 0, 0, 0);
    }
  }

  int nd[4]; float dv[4];
  #pragma unroll
  for (int r = 0; r < 4; r++) {
    nd[r] = row0 + wv * 16 + q * 4 + r;
    int c = (nd[r] < N) ? nd[r] : (N - 1);
    dv[r] = dinv[c];
  }
  #pragma unroll
  for (int ct = 0; ct < 8; ct++)
    #pragma unroll
    for (int r = 0; r < 4; r++)
      if (nd[r] < N)
        g16[((size_t)ct * (N + 1) + nd[r]) * 16 + m] = (_Float16)(acc[ct][r] * dv[r]);
}

// ---------------- XCD-sliced agg, 16 edges/iter, self included as edge -------
// Wave = 8 nodes x 8 half2-features of slice s (= blockIdx%8, XCD-pinned).
// Degrees padded to x16: 4 int4 index loads + 16 independent gathers per iter,
// 4 split accumulators, no self-term prologue, no shuffles.
__global__ __launch_bounds__(256) void k_agg_slice(
    const __half2* __restrict__ g16, const float* __restrict__ dinv,
    const int* __restrict__ base, const int* __restrict__ ssrc,
    const float* __restrict__ bias, __half2* __restrict__ hB, int N) {
  const int lane = threadIdx.x & 63;
  const int wv = threadIdx.x >> 6;
  const int s = blockIdx.x & 7;
  const int p = lane >> 3, d = lane & 7;
  const int n = (blockIdx.x >> 3) * 32 + wv * 8 + p;
  const bool act = (n < N);
  const int nc = act ? n : (N - 1);
  const __half2* table = g16 + (size_t)s * (N + 1) * 8;

  float2 a0 = {0.f, 0.f}, a1 = {0.f, 0.f}, a2 = {0.f, 0.f}, a3 = {0.f, 0.f};
  int e = base[nc], e1 = base[nc + 1];
  if (!act) e1 = e;
  for (; e < e1; e += 16) {
    int4 ia = *(const int4*)(ssrc + e);
    int4 ib = *(const int4*)(ssrc + e + 4);
    int4 ic = *(const int4*)(ssrc + e + 8);
    int4 id = *(const int4*)(ssrc + e + 12);
    float2 f0  = __half22float2(table[(size_t)ia.x * 8 + d]);
    float2 f1  = __half22float2(table[(size_t)ia.y * 8 + d]);
    float2 f2  = __half22float2(table[(size_t)ia.z * 8 + d]);
    float2 f3  = __half22float2(table[(size_t)ia.w * 8 + d]);
    float2 f4  = __half22float2(table[(size_t)ib.x * 8 + d]);
    float2 f5  = __half22float2(table[(size_t)ib.y * 8 + d]);
    float2 f6  = __half22float2(table[(size_t)ib.z * 8 + d]);
    float2 f7  = __half22float2(table[(size_t)ib.w * 8 + d]);
    float2 f8  = __half22float2(table[(size_t)ic.x * 8 + d]);
    float2 f9  = __half22float2(table[(size_t)ic.y * 8 + d]);
    float2 f10 = __half22float2(table[(size_t)ic.z * 8 + d]);
    float2 f11 = __half22float2(table[(size_t)ic.w * 8 + d]);
    float2 f12 = __half22float2(table[(size_t)id.x * 8 + d]);
    float2 f13 = __half22float2(table[(size_t)id.y * 8 + d]);
    float2 f14 = __half22float2(table[(size_t)id.z * 8 + d]);
    float2 f15 = __half22float2(table[(size_t)id.w * 8 + d]);
    a0.x += (f0.x + f1.x) + (f2.x + f3.x);   a0.y += (f0.y + f1.y) + (f2.y + f3.y);
    a1.x += (f4.x + f5.x) + (f6.x + f7.x);   a1.y += (f4.y + f5.y) + (f6.y + f7.y);
    a2.x += (f8.x + f9.x) + (f10.x + f11.x); a2.y += (f8.y + f9.y) + (f10.y + f11.y);
    a3.x += (f12.x + f13.x) + (f14.x + f15.x);
    a3.y += (f12.y + f13.y) + (f14.y + f15.y);
  }
  if (act) {
    float dvn = dinv[n];
    float2 bb = *(const float2*)(bias + s * 16 + d * 2);
    float sx = (a0.x + a1.x) + (a2.x + a3.x);
    float sy = (a0.y + a1.y) + (a2.y + a3.y);
    hB[(size_t)n * 64 + s * 8 + d] =
        __floats2half2_rn(fmaxf(sx * dvn + bb.x, 0.f), fmaxf(sy * dvn + bb.y, 0.f));
  }
}

// ---------------- layer-2 sliced agg fused with final linear -----------------
__global__ __launch_bounds__(256) void k_agg_final_slice(
    const __half2* __restrict__ g16, const float* __restrict__ dinv,
    const int* __restrict__ base, const int* __restrict__ ssrc,
    const float* __restrict__ bias, const float* __restrict__ wlin,
    const float* __restrict__ blin, float* __restrict__ out, int N) {
  const int lane = threadIdx.x & 63;
  const int wv = threadIdx.x >> 6;
  const int s = blockIdx.x & 7;
  const int p = lane >> 3, d = lane & 7;
  const int n = (blockIdx.x >> 3) * 32 + wv * 8 + p;
  const bool act = (n < N);
  const int nc = act ? n : (N - 1);
  const __half2* table = g16 + (size_t)s * (N + 1) * 8;

  float2 a0 = {0.f, 0.f}, a1 = {0.f, 0.f}, a2 = {0.f, 0.f}, a3 = {0.f, 0.f};
  int e = base[nc], e1 = base[nc + 1];
  if (!act) e1 = e;
  for (; e < e1; e += 16) {
    int4 ia = *(const int4*)(ssrc + e);
    int4 ib = *(const int4*)(ssrc + e + 4);
    int4 ic = *(const int4*)(ssrc + e + 8);
    int4 id = *(const int4*)(ssrc + e + 12);
    float2 f0  = __half22float2(table[(size_t)ia.x * 8 + d]);
    float2 f1  = __half22float2(table[(size_t)ia.y * 8 + d]);
    float2 f2  = __half22float2(table[(size_t)ia.z * 8 + d]);
    float2 f3  = __half22float2(table[(size_t)ia.w * 8 + d]);
    float2 f4  = __half22float2(table[(size_t)ib.x * 8 + d]);
    float2 f5  = __half22float2(table[(size_t)ib.y * 8 + d]);
    float2 f6  = __half22float2(table[(size_t)ib.z * 8 + d]);
    float2 f7  = __half22float2(table[(size_t)ib.w * 8 + d]);
    float2 f8  = __half22float2(table[(size_t)ic.x * 8 + d]);
    float2 f9  = __half22float2(table[(size_t)ic.y * 8 + d]);
    float2 f10 = __half22float2(table[(size_t)ic.z * 8 + d]);
    float2 f11 = __half22float2(table[(size_t)ic.w * 8 + d]);
    float2 f12 = __half22float2(table[(size_t)id.x * 8 + d]);
    float2 f13 = __half22float2(table[(size_t)id.y * 8 + d]);
    float2 f14 = __half22float2(table[(size_t)id.z * 8 + d]);
    float2 f15 = __half22float2(table[(size_t)id.w * 8 + d]);
    a0.x += (f0.x + f1.x) + (f2.x + f3.x);   a0.y += (f0.y + f1.y) + (f2.y + f3.y);
    a1.x += (f4.x + f5.x) + (f6.x + f7.x);   a1.y += (f4.y + f5.y) + (f6.y + f7.y);
    a2.x += (f8.x + f9.x) + (f10.x + f11.x); a2.y += (f8.y + f9.y) + (f10.y + f11.y);
    a3.x += (f12.x + f13.x) + (f14.x + f15.x);
    a3.y += (f12.y + f13.y) + (f14.y + f15.y);
  }
  if (act) {
    float dvn = dinv[n];
    float2 bb = *(const float2*)(bias + s * 16 + d * 2);
    float2 wl = *(const float2*)(wlin + s * 16 + d * 2);
    float sx = (a0.x + a1.x) + (a2.x + a3.x);
    float sy = (a0.y + a1.y) + (a2.y + a3.y);
    float pv = fmaxf(sx * dvn + bb.x, 0.f) * wl.x +
               fmaxf(sy * dvn + bb.y, 0.f) * wl.y;
    #pragma unroll
    for (int m = 1; m <= 4; m <<= 1) pv += __shfl_xor(pv, m, 64);
    if (d == 0) atomicAdd(out + n, pv + (s == 0 ? blin[0] : 0.f));
  }
}

extern "C" void kernel_launch(void* const* d_in, const int* in_sizes, int n_in,
                              void* d_out, int out_size, void* d_ws, size_t ws_size,
                              hipStream_t stream) {
  const float* x    = (const float*)d_in[0];
  const int*   ei   = (const int*)d_in[1];
  const float* W1   = (const float*)d_in[2];
  const float* b1   = (const float*)d_in[3];
  const float* W2   = (const float*)d_in[4];
  const float* b2   = (const float*)d_in[5];
  const float* Wlin = (const float*)d_in[6];
  const float* blin = (const float*)d_in[7];
  const int N = in_sizes[0] / NFEAT;
  const int E = in_sizes[1] / 2;
  const int* src = ei;
  const int* dst = ei + E;
  const int Epad = E + 17 * N + 16;   // E + N self-edges + up to 15N pad

  // workspace layout (4B units)
  int* ws_i = (int*)d_ws;
  size_t off = 0;
  int* deg      = ws_i + off; off += N;
  int* base     = ws_i + off; off += (size_t)N + 1;
  off = (off + 3) & ~(size_t)3;
  int* partials = ws_i + off; off += 128;
  int* ssrc     = ws_i + off; off += Epad;
  float* dinv   = (float*)(ws_i + off); off += N;
  off = (off + 3) & ~(size_t)3;
  _Float16* Wt1 = (_Float16*)(ws_i + off); off += 8192;
  _Float16* Wt2 = (_Float16*)(ws_i + off); off += 8192;
  _Float16* g16 = (_Float16*)(ws_i + off); off += (size_t)(N + 1) * 64 + 32;
  _Float16* hB  = (_Float16*)(ws_i + off); off += (size_t)N * 64;
  int* rank     = (int*)g16;   // E+N ints, consumed by k_scatter before g16 written

  hipMemsetAsync(deg, 0, (size_t)N * sizeof(int), stream);
  hipMemsetAsync(d_out, 0, (size_t)N * sizeof(float), stream);

  const int tpbE = 256;
  const int gE = (E + N + tpbE - 1) / tpbE;
  k_deg_rank<<<gE, tpbE, 0, stream>>>(dst, deg, rank, E, N);
  k_fill<<<(Epad + 255) / 256, 256, 0, stream>>>(ssrc, N, Epad);  // sentinel fill
  k_prep_w<<<128, 256, 0, stream>>>(W1, W2, Wt1, Wt2);

  const int nb = (N + 1 + 1023) / 1024;
  k_scan_blocks<<<nb, 1024, 0, stream>>>(deg, base, partials, N);
  k_scan_partials<<<1, 128, 0, stream>>>(partials, nb);
  k_finalize_base<<<((N + 1) + 255) / 256, 256, 0, stream>>>(base, partials, deg, dinv, N);
  k_scatter<<<gE, tpbE, 0, stream>>>(src, dst, rank, base, ssrc, E, N);
  k_zero_row<<<1, 128, 0, stream>>>(g16, N);   // after scatter (rank aliased g16)

  const int gg = (N + 63) / 64;
  const int ga = 8 * ((N + 31) / 32);
  // layer 1
  k_gemm_mfma<float><<<gg, 256, 0, stream>>>(x, Wt1, dinv, g16, N);
  k_agg_slice<<<ga, 256, 0, stream>>>((const __half2*)g16, dinv, base, ssrc, b1,
                                      (__half2*)hB, N);
  // layer 2 + fused final linear
  k_gemm_mfma<_Float16><<<gg, 256, 0, stream>>>(hB, Wt2, dinv, g16, N);
  k_agg_final_slice<<<ga, 256, 0, stream>>>((const __half2*)g16, dinv, base, ssrc, b2,
                                            Wlin, blin, (float*)d_out, N);
}

// Round 9
// 429.577 us; speedup vs baseline: 1.0189x; 1.0189x over previous
//
#include <hip/hip_runtime.h>
#include <hip/hip_fp16.h>

#define NFEAT 128

typedef _Float16 v8hf __attribute__((ext_vector_type(8)));
typedef float v4f __attribute__((ext_vector_type(4)));

// ---------------- degree histogram + per-edge rank (incl. self edges) --------
__global__ void k_deg_rank(const int* __restrict__ dst, int* __restrict__ deg,
                           int* __restrict__ rank, int E, int N) {
  int e = blockIdx.x * blockDim.x + threadIdx.x;
  if (e < E) rank[e] = atomicAdd(&deg[dst[e]], 1);
  else if (e < E + N) rank[e] = atomicAdd(&deg[e - E], 1);
}

// ---------------- fill ssrc with sentinel N (pad slots gather zero row) ------
__global__ void k_fill(int* __restrict__ p, int v, int n) {
  int i = blockIdx.x * 256 + threadIdx.x;
  if (i < n) p[i] = v;
}

// ---------------- W transpose + fp16 cast: Wt[n][k] = half(W[k][n]) ----------
__global__ void k_prep_w(const float* __restrict__ W1, const float* __restrict__ W2,
                         _Float16* __restrict__ Wt1, _Float16* __restrict__ Wt2) {
  int idx = blockIdx.x * 256 + threadIdx.x;     // 0..32767
  const float* W = (idx < 16384) ? W1 : W2;
  _Float16* Wt = (idx < 16384) ? Wt1 : Wt2;
  int i = idx & 16383;
  int k = i >> 7, n = i & 127;
  Wt[n * 128 + k] = (_Float16)W[k * 128 + n];
}

// ---------------- 2-level exclusive scan over degrees padded to x4 -----------
__global__ __launch_bounds__(1024) void k_scan_blocks(const int* __restrict__ deg,
    int* __restrict__ base, int* __restrict__ partials, int n) {
  __shared__ int buf[1024];
  int tid = threadIdx.x;
  int i = blockIdx.x * 1024 + tid;
  int v = (i < n) ? ((deg[i] + 3) & ~3) : 0;
  buf[tid] = v;
  __syncthreads();
  #pragma unroll
  for (int off = 1; off < 1024; off <<= 1) {
    int t = (tid >= off) ? buf[tid - off] : 0;
    __syncthreads();
    buf[tid] += t;
    __syncthreads();
  }
  if (i <= n) base[i] = buf[tid] - v;
  if (tid == 1023) partials[blockIdx.x] = buf[tid];
}

__global__ void k_scan_partials(int* __restrict__ partials, int nb) {
  __shared__ int buf[128];
  int tid = threadIdx.x;
  int v = (tid < nb) ? partials[tid] : 0;
  buf[tid] = v;
  __syncthreads();
  #pragma unroll
  for (int off = 1; off < 128; off <<= 1) {
    int t = (tid >= off) ? buf[tid - off] : 0;
    __syncthreads();
    buf[tid] += t;
    __syncthreads();
  }
  if (tid < nb) partials[tid] = buf[tid] - v;
}

__global__ void k_finalize_base(int* __restrict__ base, const int* __restrict__ partials,
    const int* __restrict__ deg, float* __restrict__ dinv, int n) {
  int i = blockIdx.x * blockDim.x + threadIdx.x;
  if (i <= n) {
    base[i] += partials[i >> 10];
    if (i < n) dinv[i] = rsqrtf((float)deg[i]);   // deg already includes self
  }
}

__global__ void k_scatter(const int* __restrict__ src, const int* __restrict__ dst,
    const int* __restrict__ rank, const int* __restrict__ base,
    int* __restrict__ ssrc, int E, int N) {
  int e = blockIdx.x * blockDim.x + threadIdx.x;
  if (e < E) ssrc[base[dst[e]] + rank[e]] = src[e];
  else if (e < E + N) { int n = e - E; ssrc[base[n] + rank[e]] = n; }
}

// ---------------- zero sentinel row N of the sliced table --------------------
__global__ void k_zero_row(_Float16* __restrict__ g16, int N) {
  int i = threadIdx.x;           // 0..127
  int s = i >> 4, m = i & 15;
  g16[((size_t)s * (N + 1) + N) * 16 + m] = (_Float16)0.f;
}

// ---------------- MFMA fp16 GEMM: g16 = sliced( (A @ W) * dinv[row] ) ---------
// Slice stride is (N+1) rows (row N = zero sentinel).
template <typename AT>
__global__ __launch_bounds__(256) void k_gemm_mfma(
    const AT* __restrict__ A, const _Float16* __restrict__ Wt,
    const float* __restrict__ dinv, _Float16* __restrict__ g16, int N) {
  __shared__ _Float16 As[64][136];
  __shared__ _Float16 Ws[128][136];
  const int tid = threadIdx.x;
  const int row0 = blockIdx.x * 64;

  if constexpr (sizeof(AT) == 4) {   // fp32 input: load + cast
    #pragma unroll
    for (int i = 0; i < 8; i++) {
      int idx = tid + i * 256;       // 0..2047
      int row = idx >> 5;
      int c4 = idx & 31;
      int gr = row0 + row; gr = (gr < N) ? gr : (N - 1);
      float4 v = *(const float4*)((const float*)A + (size_t)gr * NFEAT + c4 * 4);
      _Float16* p = &As[row][c4 * 4];
      p[0] = (_Float16)v.x; p[1] = (_Float16)v.y;
      p[2] = (_Float16)v.z; p[3] = (_Float16)v.w;
    }
  } else {                           // fp16 input: straight copy
    #pragma unroll
    for (int i = 0; i < 4; i++) {
      int idx = tid + i * 256;
      int row = idx >> 4;
      int c8 = idx & 15;
      int gr = row0 + row; gr = (gr < N) ? gr : (N - 1);
      *(uint4*)&As[row][c8 * 8] =
          *(const uint4*)((const _Float16*)A + (size_t)gr * NFEAT + c8 * 8);
    }
  }
  #pragma unroll
  for (int i = 0; i < 8; i++) {
    int idx = tid + i * 256;
    int row = idx >> 4;
    int c8 = idx & 15;
    *(uint4*)&Ws[row][c8 * 8] = *(const uint4*)(Wt + (size_t)row * 128 + c8 * 8);
  }
  __syncthreads();

  const int wv = tid >> 6;
  const int lane = tid & 63;
  const int m = lane & 15;
  const int q = lane >> 4;

  v4f acc[8] = {};
  const _Float16* arow = &As[wv * 16 + m][0];
  #pragma unroll
  for (int kt = 0; kt < 4; kt++) {
    v8hf af = *(const v8hf*)(arow + kt * 32 + q * 8);
    #pragma unroll
    for (int ct = 0; ct < 8; ct++) {
      v8hf bf = *(const v8hf*)(&Ws[ct * 16 + m][kt * 32 + q * 8]);
      acc[ct] = __builtin_amdgcn_mfma_f32_16x16x32_f16(af, bf, acc[ct], 0, 0, 0);
    }
  }

  int nd[4]; float dv[4];
  #pragma unroll
  for (int r = 0; r < 4; r++) {
    nd[r] = row0 + wv * 16 + q * 4 + r;
    int c = (nd[r] < N) ? nd[r] : (N - 1);
    dv[r] = dinv[c];
  }
  #pragma unroll
  for (int ct = 0; ct < 8; ct++)
    #pragma unroll
    for (int r = 0; r < 4; r++)
      if (nd[r] < N)
        g16[((size_t)ct * (N + 1) + nd[r]) * 16 + m] = (_Float16)(acc[ct][r] * dv[r]);
}

// ---------------- XCD-sliced agg, 16 B/lane gathers --------------------------
// Wave = 8 nodes x 8 lanes; within a node's 8 lanes: part = h&1 (features 0-7
// or 8-15), slot = h>>1 (edge pair). Per iter: int2 index load + 2 dwordx4
// gathers per lane -> 8 edges/group, only 2 addresses per edge-slice (vs 8).
// Degrees padded to x4 (pad -> zero sentinel row N).
__global__ __launch_bounds__(256) void k_agg_slice(
    const _Float16* __restrict__ g16, const float* __restrict__ dinv,
    const int* __restrict__ base, const int* __restrict__ ssrc,
    const float* __restrict__ bias, _Float16* __restrict__ hB, int N) {
  const int lane = threadIdx.x & 63;
  const int wv = threadIdx.x >> 6;
  const int s = blockIdx.x & 7;
  const int p = lane >> 3;
  const int h = lane & 7;
  const int part = h & 1;
  const int slot = h >> 1;
  const int n = (blockIdx.x >> 3) * 32 + wv * 8 + p;
  const bool act = (n < N);
  const int nc = act ? n : (N - 1);
  const _Float16* table = g16 + (size_t)s * (N + 1) * 16 + part * 8;

  float acc0[8] = {}, acc1[8] = {};
  int e = base[nc], e1 = base[nc + 1];
  if (!act) e1 = e;
  for (; e + 8 <= e1; e += 8) {
    int2 ii = *(const int2*)(ssrc + e + slot * 2);
    v8hf r0 = *(const v8hf*)(table + (size_t)ii.x * 16);
    v8hf r1 = *(const v8hf*)(table + (size_t)ii.y * 16);
    #pragma unroll
    for (int j = 0; j < 8; j++) { acc0[j] += (float)r0[j]; acc1[j] += (float)r1[j]; }
  }
  if (e < e1) {   // exactly one 4-edge group remains (x4 padding)
    int si = ssrc[e + slot];
    v8hf r0 = *(const v8hf*)(table + (size_t)si * 16);
    #pragma unroll
    for (int j = 0; j < 8; j++) acc0[j] += (float)r0[j];
  }
  float red[8];
  #pragma unroll
  for (int j = 0; j < 8; j++) {
    float v = acc0[j] + acc1[j];
    v += __shfl_xor(v, 2, 64);
    v += __shfl_xor(v, 4, 64);
    red[j] = v;
  }
  if (act && slot == 0) {
    float dvn = dinv[n];
    const float* bp = bias + s * 16 + part * 8;
    float4 bb0 = *(const float4*)(bp);
    float4 bb1 = *(const float4*)(bp + 4);
    v8hf o;
    o[0] = (_Float16)fmaxf(red[0] * dvn + bb0.x, 0.f);
    o[1] = (_Float16)fmaxf(red[1] * dvn + bb0.y, 0.f);
    o[2] = (_Float16)fmaxf(red[2] * dvn + bb0.z, 0.f);
    o[3] = (_Float16)fmaxf(red[3] * dvn + bb0.w, 0.f);
    o[4] = (_Float16)fmaxf(red[4] * dvn + bb1.x, 0.f);
    o[5] = (_Float16)fmaxf(red[5] * dvn + bb1.y, 0.f);
    o[6] = (_Float16)fmaxf(red[6] * dvn + bb1.z, 0.f);
    o[7] = (_Float16)fmaxf(red[7] * dvn + bb1.w, 0.f);
    *(v8hf*)(hB + (size_t)n * NFEAT + s * 16 + part * 8) = o;
  }
}

// ---------------- layer-2 sliced agg fused with final linear -----------------
__global__ __launch_bounds__(256) void k_agg_final_slice(
    const _Float16* __restrict__ g16, const float* __restrict__ dinv,
    const int* __restrict__ base, const int* __restrict__ ssrc,
    const float* __restrict__ bias, const float* __restrict__ wlin,
    const float* __restrict__ blin, float* __restrict__ out, int N) {
  const int lane = threadIdx.x & 63;
  const int wv = threadIdx.x >> 6;
  const int s = blockIdx.x & 7;
  const int p = lane >> 3;
  const int h = lane & 7;
  const int part = h & 1;
  const int slot = h >> 1;
  const int n = (blockIdx.x >> 3) * 32 + wv * 8 + p;
  const bool act = (n < N);
  const int nc = act ? n : (N - 1);
  const _Float16* table = g16 + (size_t)s * (N + 1) * 16 + part * 8;

  float acc0[8] = {}, acc1[8] = {};
  int e = base[nc], e1 = base[nc + 1];
  if (!act) e1 = e;
  for (; e + 8 <= e1; e += 8) {
    int2 ii = *(const int2*)(ssrc + e + slot * 2);
    v8hf r0 = *(const v8hf*)(table + (size_t)ii.x * 16);
    v8hf r1 = *(const v8hf*)(table + (size_t)ii.y * 16);
    #pragma unroll
    for (int j = 0; j < 8; j++) { acc0[j] += (float)r0[j]; acc1[j] += (float)r1[j]; }
  }
  if (e < e1) {
    int si = ssrc[e + slot];
    v8hf r0 = *(const v8hf*)(table + (size_t)si * 16);
    #pragma unroll
    for (int j = 0; j < 8; j++) acc0[j] += (float)r0[j];
  }
  float red[8];
  #pragma unroll
  for (int j = 0; j < 8; j++) {
    float v = acc0[j] + acc1[j];
    v += __shfl_xor(v, 2, 64);
    v += __shfl_xor(v, 4, 64);
    red[j] = v;
  }
  float dvn = dinv[nc];
  const float* bp = bias + s * 16 + part * 8;
  const float* wp = wlin + s * 16 + part * 8;
  float4 bb0 = *(const float4*)(bp);
  float4 bb1 = *(const float4*)(bp + 4);
  float4 wl0 = *(const float4*)(wp);
  float4 wl1 = *(const float4*)(wp + 4);
  float pv = fmaxf(red[0] * dvn + bb0.x, 0.f) * wl0.x +
             fmaxf(red[1] * dvn + bb0.y, 0.f) * wl0.y +
             fmaxf(red[2] * dvn + bb0.z, 0.f) * wl0.z +
             fmaxf(red[3] * dvn + bb0.w, 0.f) * wl0.w +
             fmaxf(red[4] * dvn + bb1.x, 0.f) * wl1.x +
             fmaxf(red[5] * dvn + bb1.y, 0.f) * wl1.y +
             fmaxf(red[6] * dvn + bb1.z, 0.f) * wl1.z +
             fmaxf(red[7] * dvn + bb1.w, 0.f) * wl1.w;
  pv += __shfl_xor(pv, 1, 64);
  if (act && h == 0) atomicAdd(out + n, pv + (s == 0 ? blin[0] : 0.f));
}

extern "C" void kernel_launch(void* const* d_in, const int* in_sizes, int n_in,
                              void* d_out, int out_size, void* d_ws, size_t ws_size,
                              hipStream_t stream) {
  const float* x    = (const float*)d_in[0];
  const int*   ei   = (const int*)d_in[1];
  const float* W1   = (const float*)d_in[2];
  const float* b1   = (const float*)d_in[3];
  const float* W2   = (const float*)d_in[4];
  const float* b2   = (const float*)d_in[5];
  const float* Wlin = (const float*)d_in[6];
  const float* blin = (const float*)d_in[7];
  const int N = in_sizes[0] / NFEAT;
  const int E = in_sizes[1] / 2;
  const int* src = ei;
  const int* dst = ei + E;
  const int Epad = E + 5 * N + 8;   // E + N self-edges + up to 3N pad

  // workspace layout (4B units)
  int* ws_i = (int*)d_ws;
  size_t off = 0;
  int* deg      = ws_i + off; off += N;
  int* base     = ws_i + off; off += (size_t)N + 1;
  off = (off + 3) & ~(size_t)3;
  int* partials = ws_i + off; off += 128;
  int* ssrc     = ws_i + off; off += Epad;
  float* dinv   = (float*)(ws_i + off); off += N;
  off = (off + 3) & ~(size_t)3;
  _Float16* Wt1 = (_Float16*)(ws_i + off); off += 8192;
  _Float16* Wt2 = (_Float16*)(ws_i + off); off += 8192;
  _Float16* g16 = (_Float16*)(ws_i + off); off += (size_t)(N + 1) * 64 + 32;
  _Float16* hB  = (_Float16*)(ws_i + off); off += (size_t)N * 64;
  int* rank     = (int*)g16;   // E+N ints, consumed by k_scatter before g16 written

  hipMemsetAsync(deg, 0, (size_t)N * sizeof(int), stream);
  hipMemsetAsync(d_out, 0, (size_t)N * sizeof(float), stream);

  const int tpbE = 256;
  const int gE = (E + N + tpbE - 1) / tpbE;
  k_deg_rank<<<gE, tpbE, 0, stream>>>(dst, deg, rank, E, N);
  k_fill<<<(Epad + 255) / 256, 256, 0, stream>>>(ssrc, N, Epad);  // sentinel fill
  k_prep_w<<<128, 256, 0, stream>>>(W1, W2, Wt1, Wt2);

  const int nb = (N + 1 + 1023) / 1024;
  k_scan_blocks<<<nb, 1024, 0, stream>>>(deg, base, partials, N);
  k_scan_partials<<<1, 128, 0, stream>>>(partials, nb);
  k_finalize_base<<<((N + 1) + 255) / 256, 256, 0, stream>>>(base, partials, deg, dinv, N);
  k_scatter<<<gE, tpbE, 0, stream>>>(src, dst, rank, base, ssrc, E, N);
  k_zero_row<<<1, 128, 0, stream>>>(g16, N);   // after scatter (rank aliased g16)

  const int gg = (N + 63) / 64;
  const int ga = 8 * ((N + 31) / 32);
  // layer 1
  k_gemm_mfma<float><<<gg, 256, 0, stream>>>(x, Wt1, dinv, g16, N);
  k_agg_slice<<<ga, 256, 0, stream>>>(g16, dinv, base, ssrc, b1, hB, N);
  // layer 2 + fused final linear
  k_gemm_mfma<_Float16><<<gg, 256, 0, stream>>>(hB, Wt2, dinv, g16, N);
  k_agg_final_slice<<<ga, 256, 0, stream>>>(g16, dinv, base, ssrc, b2,
                                            Wlin, blin, (float*)d_out, N);
}

// Round 10
// 401.217 us; speedup vs baseline: 1.0909x; 1.0707x over previous
//
#include <hip/hip_runtime.h>
#include <hip/hip_fp16.h>

#define NFEAT 128

typedef _Float16 v8hf __attribute__((ext_vector_type(8)));
typedef float v4f __attribute__((ext_vector_type(4)));

// ---------------- degree histogram + per-edge rank (incl. self edges) --------
// Threads [0,E): real edges; [E,E+N): self edge n->n. deg includes self,
// so dinv = rsqrt(deg) matches reference's deg+1.
__global__ void k_deg_rank(const int* __restrict__ dst, int* __restrict__ deg,
                           int* __restrict__ rank, int E, int N) {
  int e = blockIdx.x * blockDim.x + threadIdx.x;
  if (e < E) rank[e] = atomicAdd(&deg[dst[e]], 1);
  else if (e < E + N) rank[e] = atomicAdd(&deg[e - E], 1);
}

// ---------------- W transpose + fp16 cast: Wt[n][k] = half(W[k][n]) ----------
__global__ void k_prep_w(const float* __restrict__ W1, const float* __restrict__ W2,
                         _Float16* __restrict__ Wt1, _Float16* __restrict__ Wt2) {
  int idx = blockIdx.x * 256 + threadIdx.x;     // 0..32767
  const float* W = (idx < 16384) ? W1 : W2;
  _Float16* Wt = (idx < 16384) ? Wt1 : Wt2;
  int i = idx & 16383;
  int k = i >> 7, n = i & 127;
  Wt[n * 128 + k] = (_Float16)W[k * 128 + n];
}

// ---------------- 2-level exclusive scan over degrees ------------------------
__global__ __launch_bounds__(1024) void k_scan_blocks(const int* __restrict__ deg,
    int* __restrict__ base, int* __restrict__ partials, int n) {
  __shared__ int buf[1024];
  int tid = threadIdx.x;
  int i = blockIdx.x * 1024 + tid;
  int v = (i < n) ? deg[i] : 0;
  buf[tid] = v;
  __syncthreads();
  #pragma unroll
  for (int off = 1; off < 1024; off <<= 1) {
    int t = (tid >= off) ? buf[tid - off] : 0;
    __syncthreads();
    buf[tid] += t;
    __syncthreads();
  }
  if (i <= n) base[i] = buf[tid] - v;
  if (tid == 1023) partials[blockIdx.x] = buf[tid];
}

__global__ void k_scan_partials(int* __restrict__ partials, int nb) {
  __shared__ int buf[128];
  int tid = threadIdx.x;
  int v = (tid < nb) ? partials[tid] : 0;
  buf[tid] = v;
  __syncthreads();
  #pragma unroll
  for (int off = 1; off < 128; off <<= 1) {
    int t = (tid >= off) ? buf[tid - off] : 0;
    __syncthreads();
    buf[tid] += t;
    __syncthreads();
  }
  if (tid < nb) partials[tid] = buf[tid] - v;
}

__global__ void k_finalize_base(int* __restrict__ base, const int* __restrict__ partials,
    const int* __restrict__ deg, float* __restrict__ dinv, int n) {
  int i = blockIdx.x * blockDim.x + threadIdx.x;
  if (i <= n) {
    base[i] += partials[i >> 10];
    if (i < n) dinv[i] = rsqrtf((float)deg[i]);   // deg already includes self
  }
}

__global__ void k_scatter(const int* __restrict__ src, const int* __restrict__ dst,
    const int* __restrict__ rank, const int* __restrict__ base,
    int* __restrict__ ssrc, int E, int N) {
  int e = blockIdx.x * blockDim.x + threadIdx.x;
  if (e < E) ssrc[base[dst[e]] + rank[e]] = src[e];
  else if (e < E + N) { int n = e - E; ssrc[base[n] + rank[e]] = n; }
}

// ---------------- MFMA fp16 GEMM: g16[r][:] = half((A[r][:] @ W) * dinv[r]) --
// Block: 64 rows x 128 cols, 256 threads (4 waves), whole K=128 in LDS.
template <typename AT>
__global__ __launch_bounds__(256) void k_gemm_mfma(
    const AT* __restrict__ A, const _Float16* __restrict__ Wt,
    const float* __restrict__ dinv, _Float16* __restrict__ g16, int N) {
  __shared__ _Float16 As[64][136];
  __shared__ _Float16 Ws[128][136];
  const int tid = threadIdx.x;
  const int row0 = blockIdx.x * 64;

  if constexpr (sizeof(AT) == 4) {   // fp32 input: load + cast
    #pragma unroll
    for (int i = 0; i < 8; i++) {
      int idx = tid + i * 256;       // 0..2047
      int row = idx >> 5;
      int c4 = idx & 31;
      int gr = row0 + row; gr = (gr < N) ? gr : (N - 1);
      float4 v = *(const float4*)((const float*)A + (size_t)gr * NFEAT + c4 * 4);
      _Float16* p = &As[row][c4 * 4];
      p[0] = (_Float16)v.x; p[1] = (_Float16)v.y;
      p[2] = (_Float16)v.z; p[3] = (_Float16)v.w;
    }
  } else {                           // fp16 input: straight copy
    #pragma unroll
    for (int i = 0; i < 4; i++) {
      int idx = tid + i * 256;
      int row = idx >> 4;
      int c8 = idx & 15;
      int gr = row0 + row; gr = (gr < N) ? gr : (N - 1);
      *(uint4*)&As[row][c8 * 8] =
          *(const uint4*)((const _Float16*)A + (size_t)gr * NFEAT + c8 * 8);
    }
  }
  #pragma unroll
  for (int i = 0; i < 8; i++) {
    int idx = tid + i * 256;
    int row = idx >> 4;
    int c8 = idx & 15;
    *(uint4*)&Ws[row][c8 * 8] = *(const uint4*)(Wt + (size_t)row * 128 + c8 * 8);
  }
  __syncthreads();

  const int wv = tid >> 6;
  const int lane = tid & 63;
  const int m = lane & 15;
  const int q = lane >> 4;

  v4f acc[8] = {};
  const _Float16* arow = &As[wv * 16 + m][0];
  #pragma unroll
  for (int kt = 0; kt < 4; kt++) {
    v8hf af = *(const v8hf*)(arow + kt * 32 + q * 8);
    #pragma unroll
    for (int ct = 0; ct < 8; ct++) {
      v8hf bf = *(const v8hf*)(&Ws[ct * 16 + m][kt * 32 + q * 8]);
      acc[ct] = __builtin_amdgcn_mfma_f32_16x16x32_f16(af, bf, acc[ct], 0, 0, 0);
    }
  }

  int nd[4]; float dv[4];
  #pragma unroll
  for (int r = 0; r < 4; r++) {
    nd[r] = row0 + wv * 16 + q * 4 + r;
    int c = (nd[r] < N) ? nd[r] : (N - 1);
    dv[r] = dinv[c];
  }
  #pragma unroll
  for (int ct = 0; ct < 8; ct++)
    #pragma unroll
    for (int r = 0; r < 4; r++)
      if (nd[r] < N)
        g16[(size_t)nd[r] * NFEAT + ct * 16 + m] = (_Float16)(acc[ct][r] * dv[r]);
}

// ---------------- agg: wave per node, full 256-B row gathers -----------------
// 64 lanes x half2 = one full 128-feature row per gather instr. Wave-uniform
// loop bounds (no divergence); ssrc loads are wave-uniform -> scalar loads.
// Self term arrives via the CSR self-edge. out = relu(dinv*sum + b) in fp16.
__global__ __launch_bounds__(256) void k_agg(
    const __half2* __restrict__ g, const float* __restrict__ dinv,
    const int* __restrict__ base, const int* __restrict__ ssrc,
    const float* __restrict__ bias, __half2* __restrict__ hB, int N) {
  const int lane = threadIdx.x & 63;
  const int n = blockIdx.x * 4 + (threadIdx.x >> 6);
  if (n >= N) return;
  int e = base[n], b1 = base[n + 1];
  float2 acc = make_float2(0.f, 0.f);
  for (; e + 8 <= b1; e += 8) {
    int s0 = ssrc[e],     s1 = ssrc[e + 1], s2 = ssrc[e + 2], s3 = ssrc[e + 3];
    int s4 = ssrc[e + 4], s5 = ssrc[e + 5], s6 = ssrc[e + 6], s7 = ssrc[e + 7];
    float2 f0 = __half22float2(g[(size_t)s0 * 64 + lane]);
    float2 f1 = __half22float2(g[(size_t)s1 * 64 + lane]);
    float2 f2 = __half22float2(g[(size_t)s2 * 64 + lane]);
    float2 f3 = __half22float2(g[(size_t)s3 * 64 + lane]);
    float2 f4 = __half22float2(g[(size_t)s4 * 64 + lane]);
    float2 f5 = __half22float2(g[(size_t)s5 * 64 + lane]);
    float2 f6 = __half22float2(g[(size_t)s6 * 64 + lane]);
    float2 f7 = __half22float2(g[(size_t)s7 * 64 + lane]);
    acc.x += (f0.x + f1.x) + (f2.x + f3.x) + (f4.x + f5.x) + (f6.x + f7.x);
    acc.y += (f0.y + f1.y) + (f2.y + f3.y) + (f4.y + f5.y) + (f6.y + f7.y);
  }
  for (; e < b1; ++e) {
    float2 f = __half22float2(g[(size_t)ssrc[e] * 64 + lane]);
    acc.x += f.x; acc.y += f.y;
  }
  float dvn = dinv[n];
  float2 bb = *(const float2*)(bias + lane * 2);
  hB[(size_t)n * 64 + lane] =
      __floats2half2_rn(fmaxf(acc.x * dvn + bb.x, 0.f),
                        fmaxf(acc.y * dvn + bb.y, 0.f));
}

// ---------------- layer-2 agg fused with final linear (wave per node) --------
// Full in-wave reduction -> plain store, no atomics, no output memset.
__global__ __launch_bounds__(256) void k_agg_final(
    const __half2* __restrict__ g, const float* __restrict__ dinv,
    const int* __restrict__ base, const int* __restrict__ ssrc,
    const float* __restrict__ bias, const float* __restrict__ wlin,
    const float* __restrict__ blin, float* __restrict__ out, int N) {
  const int lane = threadIdx.x & 63;
  const int n = blockIdx.x * 4 + (threadIdx.x >> 6);
  if (n >= N) return;
  int e = base[n], b1 = base[n + 1];
  float2 acc = make_float2(0.f, 0.f);
  for (; e + 8 <= b1; e += 8) {
    int s0 = ssrc[e],     s1 = ssrc[e + 1], s2 = ssrc[e + 2], s3 = ssrc[e + 3];
    int s4 = ssrc[e + 4], s5 = ssrc[e + 5], s6 = ssrc[e + 6], s7 = ssrc[e + 7];
    float2 f0 = __half22float2(g[(size_t)s0 * 64 + lane]);
    float2 f1 = __half22float2(g[(size_t)s1 * 64 + lane]);
    float2 f2 = __half22float2(g[(size_t)s2 * 64 + lane]);
    float2 f3 = __half22float2(g[(size_t)s3 * 64 + lane]);
    float2 f4 = __half22float2(g[(size_t)s4 * 64 + lane]);
    float2 f5 = __half22float2(g[(size_t)s5 * 64 + lane]);
    float2 f6 = __half22float2(g[(size_t)s6 * 64 + lane]);
    float2 f7 = __half22float2(g[(size_t)s7 * 64 + lane]);
    acc.x += (f0.x + f1.x) + (f2.x + f3.x) + (f4.x + f5.x) + (f6.x + f7.x);
    acc.y += (f0.y + f1.y) + (f2.y + f3.y) + (f4.y + f5.y) + (f6.y + f7.y);
  }
  for (; e < b1; ++e) {
    float2 f = __half22float2(g[(size_t)ssrc[e] * 64 + lane]);
    acc.x += f.x; acc.y += f.y;
  }
  float dvn = dinv[n];
  float2 bb = *(const float2*)(bias + lane * 2);
  float2 wl = *(const float2*)(wlin + lane * 2);
  float pv = fmaxf(acc.x * dvn + bb.x, 0.f) * wl.x +
             fmaxf(acc.y * dvn + bb.y, 0.f) * wl.y;
  #pragma unroll
  for (int off = 32; off >= 1; off >>= 1) pv += __shfl_down(pv, off, 64);
  if (lane == 0) out[n] = pv + blin[0];
}

extern "C" void kernel_launch(void* const* d_in, const int* in_sizes, int n_in,
                              void* d_out, int out_size, void* d_ws, size_t ws_size,
                              hipStream_t stream) {
  const float* x    = (const float*)d_in[0];
  const int*   ei   = (const int*)d_in[1];
  const float* W1   = (const float*)d_in[2];
  const float* b1   = (const float*)d_in[3];
  const float* W2   = (const float*)d_in[4];
  const float* b2   = (const float*)d_in[5];
  const float* Wlin = (const float*)d_in[6];
  const float* blin = (const float*)d_in[7];
  const int N = in_sizes[0] / NFEAT;
  const int E = in_sizes[1] / 2;
  const int* src = ei;
  const int* dst = ei + E;
  const int Etot = E + N;   // real edges + self edges

  // workspace layout (4B units)
  int* ws_i = (int*)d_ws;
  size_t off = 0;
  int* deg      = ws_i + off; off += N;
  int* base     = ws_i + off; off += (size_t)N + 1;
  off = (off + 3) & ~(size_t)3;
  int* partials = ws_i + off; off += 128;
  int* ssrc     = ws_i + off; off += Etot;
  float* dinv   = (float*)(ws_i + off); off += N;
  off = (off + 3) & ~(size_t)3;
  _Float16* Wt1 = (_Float16*)(ws_i + off); off += 8192;
  _Float16* Wt2 = (_Float16*)(ws_i + off); off += 8192;
  _Float16* g16 = (_Float16*)(ws_i + off); off += (size_t)N * 64;   // N x 128 fp16
  _Float16* hB  = (_Float16*)(ws_i + off); off += (size_t)N * 64;
  int* rank     = (int*)g16;   // Etot ints, consumed by k_scatter before g16 written

  hipMemsetAsync(deg, 0, (size_t)N * sizeof(int), stream);

  const int tpbE = 256;
  const int gE = (Etot + tpbE - 1) / tpbE;
  k_deg_rank<<<gE, tpbE, 0, stream>>>(dst, deg, rank, E, N);
  k_prep_w<<<128, 256, 0, stream>>>(W1, W2, Wt1, Wt2);

  const int nb = (N + 1 + 1023) / 1024;
  k_scan_blocks<<<nb, 1024, 0, stream>>>(deg, base, partials, N);
  k_scan_partials<<<1, 128, 0, stream>>>(partials, nb);
  k_finalize_base<<<((N + 1) + 255) / 256, 256, 0, stream>>>(base, partials, deg, dinv, N);
  k_scatter<<<gE, tpbE, 0, stream>>>(src, dst, rank, base, ssrc, E, N);

  const int gg = (N + 63) / 64;
  const int ga = (N + 3) / 4;
  // layer 1
  k_gemm_mfma<float><<<gg, 256, 0, stream>>>(x, Wt1, dinv, g16, N);
  k_agg<<<ga, 256, 0, stream>>>((const __half2*)g16, dinv, base, ssrc, b1,
                                (__half2*)hB, N);
  // layer 2 + fused final linear
  k_gemm_mfma<_Float16><<<gg, 256, 0, stream>>>(hB, Wt2, dinv, g16, N);
  k_agg_final<<<ga, 256, 0, stream>>>((const __half2*)g16, dinv, base, ssrc, b2,
                                      Wlin, blin, (float*)d_out, N);
}

// Round 11
// 386.892 us; speedup vs baseline: 1.1313x; 1.0370x over previous
//
#include <hip/hip_runtime.h>
#include <hip/hip_fp16.h>

#define NFEAT 128

typedef _Float16 v8hf __attribute__((ext_vector_type(8)));
typedef float v4f __attribute__((ext_vector_type(4)));

// ------- degree histogram + per-edge rank (incl. self edges) + W prep --------
// Threads [0,E): real edges; [E,E+N): self edges; [E+N, E+N+32768): W1/W2
// transpose+fp16 cast (merged to save a dispatch).
__global__ void k_deg_rank_w(const int* __restrict__ dst, int* __restrict__ deg,
                             int* __restrict__ rank, int E, int N,
                             const float* __restrict__ W1, const float* __restrict__ W2,
                             _Float16* __restrict__ Wt1, _Float16* __restrict__ Wt2) {
  int e = blockIdx.x * blockDim.x + threadIdx.x;
  if (e < E) rank[e] = atomicAdd(&deg[dst[e]], 1);
  else if (e < E + N) rank[e] = atomicAdd(&deg[e - E], 1);
  else if (e < E + N + 32768) {
    int idx = e - E - N;             // 0..32767
    const float* W = (idx < 16384) ? W1 : W2;
    _Float16* Wt = (idx < 16384) ? Wt1 : Wt2;
    int i = idx & 16383;
    int k = i >> 7, n = i & 127;
    Wt[n * 128 + k] = (_Float16)W[k * 128 + n];
  }
}

// ---------------- 2-level exclusive scan over degrees ------------------------
__global__ __launch_bounds__(1024) void k_scan_blocks(const int* __restrict__ deg,
    int* __restrict__ base, int* __restrict__ partials, int n) {
  __shared__ int buf[1024];
  int tid = threadIdx.x;
  int i = blockIdx.x * 1024 + tid;
  int v = (i < n) ? deg[i] : 0;
  buf[tid] = v;
  __syncthreads();
  #pragma unroll
  for (int off = 1; off < 1024; off <<= 1) {
    int t = (tid >= off) ? buf[tid - off] : 0;
    __syncthreads();
    buf[tid] += t;
    __syncthreads();
  }
  if (i <= n) base[i] = buf[tid] - v;
  if (tid == 1023) partials[blockIdx.x] = buf[tid];
}

__global__ void k_scan_partials(int* __restrict__ partials, int nb) {
  __shared__ int buf[128];
  int tid = threadIdx.x;
  int v = (tid < nb) ? partials[tid] : 0;
  buf[tid] = v;
  __syncthreads();
  #pragma unroll
  for (int off = 1; off < 128; off <<= 1) {
    int t = (tid >= off) ? buf[tid - off] : 0;
    __syncthreads();
    buf[tid] += t;
    __syncthreads();
  }
  if (tid < nb) partials[tid] = buf[tid] - v;
}

__global__ void k_finalize_base(int* __restrict__ base, const int* __restrict__ partials,
    const int* __restrict__ deg, float* __restrict__ dinv, int n) {
  int i = blockIdx.x * blockDim.x + threadIdx.x;
  if (i <= n) {
    base[i] += partials[i >> 10];
    if (i < n) dinv[i] = rsqrtf((float)deg[i]);   // deg already includes self
  }
}

__global__ void k_scatter(const int* __restrict__ src, const int* __restrict__ dst,
    const int* __restrict__ rank, const int* __restrict__ base,
    int* __restrict__ ssrc, int E, int N) {
  int e = blockIdx.x * blockDim.x + threadIdx.x;
  if (e < E) ssrc[base[dst[e]] + rank[e]] = src[e];
  else if (e < E + N) { int n = e - E; ssrc[base[n] + rank[e]] = n; }
}

// ---------------- MFMA fp16 GEMM: g16[r][:] = half((A[r][:] @ W) * dinv[r]) --
// Block: 64 rows x 128 cols, 256 threads (4 waves), whole K=128 in LDS.
// Block 0 also zeroes the sentinel row N (gathered by clamped tail edges).
template <typename AT>
__global__ __launch_bounds__(256) void k_gemm_mfma(
    const AT* __restrict__ A, const _Float16* __restrict__ Wt,
    const float* __restrict__ dinv, _Float16* __restrict__ g16, int N) {
  __shared__ _Float16 As[64][136];
  __shared__ _Float16 Ws[128][136];
  const int tid = threadIdx.x;
  const int row0 = blockIdx.x * 64;

  if (blockIdx.x == 0 && tid < 16) {   // zero sentinel row N
    v8hf z;
    #pragma unroll
    for (int j = 0; j < 8; j++) z[j] = (_Float16)0.f;
    *(v8hf*)(g16 + (size_t)N * NFEAT + tid * 8) = z;
  }

  if constexpr (sizeof(AT) == 4) {   // fp32 input: load + cast
    #pragma unroll
    for (int i = 0; i < 8; i++) {
      int idx = tid + i * 256;       // 0..2047
      int row = idx >> 5;
      int c4 = idx & 31;
      int gr = row0 + row; gr = (gr < N) ? gr : (N - 1);
      float4 v = *(const float4*)((const float*)A + (size_t)gr * NFEAT + c4 * 4);
      _Float16* p = &As[row][c4 * 4];
      p[0] = (_Float16)v.x; p[1] = (_Float16)v.y;
      p[2] = (_Float16)v.z; p[3] = (_Float16)v.w;
    }
  } else {                           // fp16 input: straight copy
    #pragma unroll
    for (int i = 0; i < 4; i++) {
      int idx = tid + i * 256;
      int row = idx >> 4;
      int c8 = idx & 15;
      int gr = row0 + row; gr = (gr < N) ? gr : (N - 1);
      *(uint4*)&As[row][c8 * 8] =
          *(const uint4*)((const _Float16*)A + (size_t)gr * NFEAT + c8 * 8);
    }
  }
  #pragma unroll
  for (int i = 0; i < 8; i++) {
    int idx = tid + i * 256;
    int row = idx >> 4;
    int c8 = idx & 15;
    *(uint4*)&Ws[row][c8 * 8] = *(const uint4*)(Wt + (size_t)row * 128 + c8 * 8);
  }
  __syncthreads();

  const int wv = tid >> 6;
  const int lane = tid & 63;
  const int m = lane & 15;
  const int q = lane >> 4;

  v4f acc[8] = {};
  const _Float16* arow = &As[wv * 16 + m][0];
  #pragma unroll
  for (int kt = 0; kt < 4; kt++) {
    v8hf af = *(const v8hf*)(arow + kt * 32 + q * 8);
    #pragma unroll
    for (int ct = 0; ct < 8; ct++) {
      v8hf bf = *(const v8hf*)(&Ws[ct * 16 + m][kt * 32 + q * 8]);
      acc[ct] = __builtin_amdgcn_mfma_f32_16x16x32_f16(af, bf, acc[ct], 0, 0, 0);
    }
  }

  int nd[4]; float dv[4];
  #pragma unroll
  for (int r = 0; r < 4; r++) {
    nd[r] = row0 + wv * 16 + q * 4 + r;
    int c = (nd[r] < N) ? nd[r] : (N - 1);
    dv[r] = dinv[c];
  }
  #pragma unroll
  for (int ct = 0; ct < 8; ct++)
    #pragma unroll
    for (int r = 0; r < 4; r++)
      if (nd[r] < N)
        g16[(size_t)nd[r] * NFEAT + ct * 16 + m] = (_Float16)(acc[ct][r] * dv[r]);
}

// ---------------- agg: wave per node, 4 edge-rows per gather instr -----------
// Lane = (gq = lane>>4: edge group, l = lane&15: features l*8..l*8+7).
// Each gather instr: 16 B/lane covers 4 full 256-B rows -> 4x fewer VMEM
// instrs than half2/lane. Lane-private fp32 accum; xor(16,32) group reduce.
// Tail edges clamp to zero sentinel row N. Self term is a CSR self-edge.
__global__ __launch_bounds__(256) void k_agg(
    const _Float16* __restrict__ g, const float* __restrict__ dinv,
    const int* __restrict__ base, const int* __restrict__ ssrc,
    const float* __restrict__ bias, _Float16* __restrict__ hB, int N) {
  const int lane = threadIdx.x & 63;
  const int n = blockIdx.x * 4 + (threadIdx.x >> 6);
  if (n >= N) return;
  const int gq = lane >> 4;
  const int l = lane & 15;
  float acc[8] = {};
  int b0 = base[n], b1 = base[n + 1];
  for (int e = b0; e < b1; e += 8) {
    int e0 = e + gq, e1 = e + 4 + gq;
    int i0 = ssrc[e0];               // ssrc has +8 slack, loads are safe
    int i1 = ssrc[e1];
    i0 = (e0 < b1) ? i0 : N;         // clamp to zero sentinel row
    i1 = (e1 < b1) ? i1 : N;
    v8hf r0 = *(const v8hf*)(g + (size_t)i0 * NFEAT + l * 8);
    v8hf r1 = *(const v8hf*)(g + (size_t)i1 * NFEAT + l * 8);
    #pragma unroll
    for (int j = 0; j < 8; j++) acc[j] += (float)r0[j] + (float)r1[j];
  }
  #pragma unroll
  for (int j = 0; j < 8; j++) {
    acc[j] += __shfl_xor(acc[j], 16, 64);
    acc[j] += __shfl_xor(acc[j], 32, 64);
  }
  if (gq == 0) {                     // lanes 0..15 write the 256-B row
    float dvn = dinv[n];
    const float* bp = bias + l * 8;
    float4 bb0 = *(const float4*)(bp);
    float4 bb1 = *(const float4*)(bp + 4);
    float bv[8] = {bb0.x, bb0.y, bb0.z, bb0.w, bb1.x, bb1.y, bb1.z, bb1.w};
    v8hf o;
    #pragma unroll
    for (int j = 0; j < 8; j++)
      o[j] = (_Float16)fmaxf(acc[j] * dvn + bv[j], 0.f);
    *(v8hf*)(hB + (size_t)n * NFEAT + l * 8) = o;
  }
}

// ---------------- layer-2 agg fused with final linear ------------------------
__global__ __launch_bounds__(256) void k_agg_final(
    const _Float16* __restrict__ g, const float* __restrict__ dinv,
    const int* __restrict__ base, const int* __restrict__ ssrc,
    const float* __restrict__ bias, const float* __restrict__ wlin,
    const float* __restrict__ blin, float* __restrict__ out, int N) {
  const int lane = threadIdx.x & 63;
  const int n = blockIdx.x * 4 + (threadIdx.x >> 6);
  if (n >= N) return;
  const int gq = lane >> 4;
  const int l = lane & 15;
  float acc[8] = {};
  int b0 = base[n], b1 = base[n + 1];
  for (int e = b0; e < b1; e += 8) {
    int e0 = e + gq, e1 = e + 4 + gq;
    int i0 = ssrc[e0];
    int i1 = ssrc[e1];
    i0 = (e0 < b1) ? i0 : N;
    i1 = (e1 < b1) ? i1 : N;
    v8hf r0 = *(const v8hf*)(g + (size_t)i0 * NFEAT + l * 8);
    v8hf r1 = *(const v8hf*)(g + (size_t)i1 * NFEAT + l * 8);
    #pragma unroll
    for (int j = 0; j < 8; j++) acc[j] += (float)r0[j] + (float)r1[j];
  }
  #pragma unroll
  for (int j = 0; j < 8; j++) {
    acc[j] += __shfl_xor(acc[j], 16, 64);
    acc[j] += __shfl_xor(acc[j], 32, 64);
  }
  float dvn = dinv[n];
  const float* bp = bias + l * 8;
  const float* wp = wlin + l * 8;
  float4 bb0 = *(const float4*)(bp);
  float4 bb1 = *(const float4*)(bp + 4);
  float4 wl0 = *(const float4*)(wp);
  float4 wl1 = *(const float4*)(wp + 4);
  float bv[8] = {bb0.x, bb0.y, bb0.z, bb0.w, bb1.x, bb1.y, bb1.z, bb1.w};
  float wv[8] = {wl0.x, wl0.y, wl0.z, wl0.w, wl1.x, wl1.y, wl1.z, wl1.w};
  float pv = 0.f;
  #pragma unroll
  for (int j = 0; j < 8; j++)
    pv += fmaxf(acc[j] * dvn + bv[j], 0.f) * wv[j];
  pv += __shfl_xor(pv, 1, 64);
  pv += __shfl_xor(pv, 2, 64);
  pv += __shfl_xor(pv, 4, 64);
  pv += __shfl_xor(pv, 8, 64);
  if (lane == 0) out[n] = pv + blin[0];
}

extern "C" void kernel_launch(void* const* d_in, const int* in_sizes, int n_in,
                              void* d_out, int out_size, void* d_ws, size_t ws_size,
                              hipStream_t stream) {
  const float* x    = (const float*)d_in[0];
  const int*   ei   = (const int*)d_in[1];
  const float* W1   = (const float*)d_in[2];
  const float* b1   = (const float*)d_in[3];
  const float* W2   = (const float*)d_in[4];
  const float* b2   = (const float*)d_in[5];
  const float* Wlin = (const float*)d_in[6];
  const float* blin = (const float*)d_in[7];
  const int N = in_sizes[0] / NFEAT;
  const int E = in_sizes[1] / 2;
  const int* src = ei;
  const int* dst = ei + E;
  const int Etot = E + N;   // real edges + self edges

  // workspace layout (4B units)
  int* ws_i = (int*)d_ws;
  size_t off = 0;
  int* deg      = ws_i + off; off += N;
  int* base     = ws_i + off; off += (size_t)N + 1;
  off = (off + 3) & ~(size_t)3;
  int* partials = ws_i + off; off += 128;
  int* ssrc     = ws_i + off; off += Etot + 8;   // +8 slack for tail loads
  float* dinv   = (float*)(ws_i + off); off += N;
  off = (off + 3) & ~(size_t)3;
  _Float16* Wt1 = (_Float16*)(ws_i + off); off += 8192;
  _Float16* Wt2 = (_Float16*)(ws_i + off); off += 8192;
  _Float16* g16 = (_Float16*)(ws_i + off); off += (size_t)(N + 1) * 64;  // +sentinel
  _Float16* hB  = (_Float16*)(ws_i + off); off += (size_t)N * 64;
  int* rank     = (int*)g16;   // Etot ints, consumed by k_scatter before g16 written

  hipMemsetAsync(deg, 0, (size_t)N * sizeof(int), stream);

  const int tpbE = 256;
  const int gE = (Etot + 32768 + tpbE - 1) / tpbE;
  k_deg_rank_w<<<gE, tpbE, 0, stream>>>(dst, deg, rank, E, N, W1, W2, Wt1, Wt2);

  const int nb = (N + 1 + 1023) / 1024;
  k_scan_blocks<<<nb, 1024, 0, stream>>>(deg, base, partials, N);
  k_scan_partials<<<1, 128, 0, stream>>>(partials, nb);
  k_finalize_base<<<((N + 1) + 255) / 256, 256, 0, stream>>>(base, partials, deg, dinv, N);
  k_scatter<<<(Etot + tpbE - 1) / tpbE, tpbE, 0, stream>>>(src, dst, rank, base, ssrc, E, N);

  const int gg = (N + 63) / 64;
  const int ga = (N + 3) / 4;
  // layer 1
  k_gemm_mfma<float><<<gg, 256, 0, stream>>>(x, Wt1, dinv, g16, N);
  k_agg<<<ga, 256, 0, stream>>>(g16, dinv, base, ssrc, b1, hB, N);
  // layer 2 + fused final linear
  k_gemm_mfma<_Float16><<<gg, 256, 0, stream>>>(hB, Wt2, dinv, g16, N);
  k_agg_final<<<ga, 256, 0, stream>>>(g16, dinv, base, ssrc, b2,
                                      Wlin, blin, (float*)d_out, N);
}

// Round 12
// 383.998 us; speedup vs baseline: 1.1398x; 1.0075x over previous
//
#include <hip/hip_runtime.h>
#include <hip/hip_fp16.h>

#define NFEAT 128

typedef _Float16 v8hf __attribute__((ext_vector_type(8)));
typedef float v4f __attribute__((ext_vector_type(4)));

// ------- degree histogram + per-edge rank (incl. self edges) + W prep --------
__global__ void k_deg_rank_w(const int* __restrict__ dst, int* __restrict__ deg,
                             int* __restrict__ rank, int E, int N,
                             const float* __restrict__ W1, const float* __restrict__ W2,
                             _Float16* __restrict__ Wt1, _Float16* __restrict__ Wt2) {
  int e = blockIdx.x * blockDim.x + threadIdx.x;
  if (e < E) rank[e] = atomicAdd(&deg[dst[e]], 1);
  else if (e < E + N) rank[e] = atomicAdd(&deg[e - E], 1);
  else if (e < E + N + 32768) {
    int idx = e - E - N;             // 0..32767
    const float* W = (idx < 16384) ? W1 : W2;
    _Float16* Wt = (idx < 16384) ? Wt1 : Wt2;
    int i = idx & 16383;
    int k = i >> 7, n = i & 127;
    Wt[n * 128 + k] = (_Float16)W[k * 128 + n];
  }
}

// ---------------- 2-level exclusive scan over degrees ------------------------
__global__ __launch_bounds__(1024) void k_scan_blocks(const int* __restrict__ deg,
    int* __restrict__ base, int* __restrict__ partials, int n) {
  __shared__ int buf[1024];
  int tid = threadIdx.x;
  int i = blockIdx.x * 1024 + tid;
  int v = (i < n) ? deg[i] : 0;
  buf[tid] = v;
  __syncthreads();
  #pragma unroll
  for (int off = 1; off < 1024; off <<= 1) {
    int t = (tid >= off) ? buf[tid - off] : 0;
    __syncthreads();
    buf[tid] += t;
    __syncthreads();
  }
  if (i <= n) base[i] = buf[tid] - v;
  if (tid == 1023) partials[blockIdx.x] = buf[tid];
}

__global__ void k_scan_partials(int* __restrict__ partials, int nb) {
  __shared__ int buf[128];
  int tid = threadIdx.x;
  int v = (tid < nb) ? partials[tid] : 0;
  buf[tid] = v;
  __syncthreads();
  #pragma unroll
  for (int off = 1; off < 128; off <<= 1) {
    int t = (tid >= off) ? buf[tid - off] : 0;
    __syncthreads();
    buf[tid] += t;
    __syncthreads();
  }
  if (tid < nb) partials[tid] = buf[tid] - v;
}

__global__ void k_finalize_base(int* __restrict__ base, const int* __restrict__ partials,
    const int* __restrict__ deg, float* __restrict__ dinv, int n) {
  int i = blockIdx.x * blockDim.x + threadIdx.x;
  if (i <= n) {
    base[i] += partials[i >> 10];
    if (i < n) dinv[i] = rsqrtf((float)deg[i]);   // deg already includes self
  }
}

__global__ void k_scatter(const int* __restrict__ src, const int* __restrict__ dst,
    const int* __restrict__ rank, const int* __restrict__ base,
    int* __restrict__ ssrc, int E, int N) {
  int e = blockIdx.x * blockDim.x + threadIdx.x;
  if (e < E) ssrc[base[dst[e]] + rank[e]] = src[e];
  else if (e < E + N) { int n = e - E; ssrc[base[n] + rank[e]] = n; }
}

// ---------------- MFMA fp16 GEMM: g16[r][:] = half((A[r][:] @ W) * dinv[r]) --
template <typename AT>
__global__ __launch_bounds__(256) void k_gemm_mfma(
    const AT* __restrict__ A, const _Float16* __restrict__ Wt,
    const float* __restrict__ dinv, _Float16* __restrict__ g16, int N) {
  __shared__ _Float16 As[64][136];
  __shared__ _Float16 Ws[128][136];
  const int tid = threadIdx.x;
  const int row0 = blockIdx.x * 64;

  if (blockIdx.x == 0 && tid < 16) {   // zero sentinel row N
    v8hf z;
    #pragma unroll
    for (int j = 0; j < 8; j++) z[j] = (_Float16)0.f;
    *(v8hf*)(g16 + (size_t)N * NFEAT + tid * 8) = z;
  }

  if constexpr (sizeof(AT) == 4) {   // fp32 input: load + cast
    #pragma unroll
    for (int i = 0; i < 8; i++) {
      int idx = tid + i * 256;       // 0..2047
      int row = idx >> 5;
      int c4 = idx & 31;
      int gr = row0 + row; gr = (gr < N) ? gr : (N - 1);
      float4 v = *(const float4*)((const float*)A + (size_t)gr * NFEAT + c4 * 4);
      _Float16* p = &As[row][c4 * 4];
      p[0] = (_Float16)v.x; p[1] = (_Float16)v.y;
      p[2] = (_Float16)v.z; p[3] = (_Float16)v.w;
    }
  } else {                           // fp16 input: straight copy
    #pragma unroll
    for (int i = 0; i < 4; i++) {
      int idx = tid + i * 256;
      int row = idx >> 4;
      int c8 = idx & 15;
      int gr = row0 + row; gr = (gr < N) ? gr : (N - 1);
      *(uint4*)&As[row][c8 * 8] =
          *(const uint4*)((const _Float16*)A + (size_t)gr * NFEAT + c8 * 8);
    }
  }
  #pragma unroll
  for (int i = 0; i < 8; i++) {
    int idx = tid + i * 256;
    int row = idx >> 4;
    int c8 = idx & 15;
    *(uint4*)&Ws[row][c8 * 8] = *(const uint4*)(Wt + (size_t)row * 128 + c8 * 8);
  }
  __syncthreads();

  const int wv = tid >> 6;
  const int lane = tid & 63;
  const int m = lane & 15;
  const int q = lane >> 4;

  v4f acc[8] = {};
  const _Float16* arow = &As[wv * 16 + m][0];
  #pragma unroll
  for (int kt = 0; kt < 4; kt++) {
    v8hf af = *(const v8hf*)(arow + kt * 32 + q * 8);
    #pragma unroll
    for (int ct = 0; ct < 8; ct++) {
      v8hf bf = *(const v8hf*)(&Ws[ct * 16 + m][kt * 32 + q * 8]);
      acc[ct] = __builtin_amdgcn_mfma_f32_16x16x32_f16(af, bf, acc[ct], 0, 0, 0);
    }
  }

  int nd[4]; float dv[4];
  #pragma unroll
  for (int r = 0; r < 4; r++) {
    nd[r] = row0 + wv * 16 + q * 4 + r;
    int c = (nd[r] < N) ? nd[r] : (N - 1);
    dv[r] = dinv[c];
  }
  #pragma unroll
  for (int ct = 0; ct < 8; ct++)
    #pragma unroll
    for (int r = 0; r < 4; r++)
      if (nd[r] < N)
        g16[(size_t)nd[r] * NFEAT + ct * 16 + m] = (_Float16)(acc[ct][r] * dv[r]);
}

// ---------------- agg: wave per node, depth-2 pipelined gathers --------------
// Lane = (gq = lane>>4: edge slot, l = lane&15: features l*8..l*8+7). One
// gather instr = 4 full 256-B rows. Pipeline: iter k+1's gathers issue BEFORE
// consuming iter k's rows; iter k+2's index loads overlap both. All branches
// wave-uniform. Tail edges clamp to zero sentinel row N.
__global__ __launch_bounds__(256) void k_agg(
    const _Float16* __restrict__ g, const float* __restrict__ dinv,
    const int* __restrict__ base, const int* __restrict__ ssrc,
    const float* __restrict__ bias, _Float16* __restrict__ hB, int N) {
  const int lane = threadIdx.x & 63;
  const int n = blockIdx.x * 4 + (threadIdx.x >> 6);
  if (n >= N) return;
  const int gq = lane >> 4;
  const int l = lane & 15;
  const int b0 = base[n], b1 = base[n + 1];

  // iter0 indices + gathers
  int e = b0;
  int p0 = e + gq, p1 = e + 4 + gq;
  int i0 = ssrc[p0], i1 = ssrc[p1];          // +8 slack makes loads safe
  i0 = (p0 < b1) ? i0 : N;
  i1 = (p1 < b1) ? i1 : N;
  v8hf r0 = *(const v8hf*)(g + (size_t)i0 * NFEAT + l * 8);
  v8hf r1 = *(const v8hf*)(g + (size_t)i1 * NFEAT + l * 8);
  // iter1 indices
  int e2 = e + 8;
  int j0 = N, j1 = N;
  if (e2 < b1) {
    int q0 = e2 + gq, q1 = e2 + 4 + gq;
    j0 = ssrc[q0]; j1 = ssrc[q1];
    j0 = (q0 < b1) ? j0 : N;
    j1 = (q1 < b1) ? j1 : N;
  }

  float acc[8] = {};
  while (true) {
    bool more = (e2 < b1);
    v8hf s0, s1;
    if (more) {                       // issue iter k+1 gathers before consuming k
      s0 = *(const v8hf*)(g + (size_t)j0 * NFEAT + l * 8);
      s1 = *(const v8hf*)(g + (size_t)j1 * NFEAT + l * 8);
    }
    int e3 = e2 + 8;
    int c0 = N, c1 = N;
    if (e3 < b1) {                    // iter k+2 indices
      int q0 = e3 + gq, q1 = e3 + 4 + gq;
      c0 = ssrc[q0]; c1 = ssrc[q1];
      c0 = (q0 < b1) ? c0 : N;
      c1 = (q1 < b1) ? c1 : N;
    }
    #pragma unroll
    for (int j = 0; j < 8; j++) acc[j] += (float)r0[j] + (float)r1[j];
    if (!more) break;
    r0 = s0; r1 = s1;
    j0 = c0; j1 = c1;
    e2 = e3;
  }

  #pragma unroll
  for (int j = 0; j < 8; j++) {
    acc[j] += __shfl_xor(acc[j], 16, 64);
    acc[j] += __shfl_xor(acc[j], 32, 64);
  }
  if (gq == 0) {
    float dvn = dinv[n];
    const float* bp = bias + l * 8;
    float4 bb0 = *(const float4*)(bp);
    float4 bb1 = *(const float4*)(bp + 4);
    float bv[8] = {bb0.x, bb0.y, bb0.z, bb0.w, bb1.x, bb1.y, bb1.z, bb1.w};
    v8hf o;
    #pragma unroll
    for (int j = 0; j < 8; j++)
      o[j] = (_Float16)fmaxf(acc[j] * dvn + bv[j], 0.f);
    *(v8hf*)(hB + (size_t)n * NFEAT + l * 8) = o;
  }
}

// ---------------- layer-2 agg fused with final linear (same pipeline) --------
__global__ __launch_bounds__(256) void k_agg_final(
    const _Float16* __restrict__ g, const float* __restrict__ dinv,
    const int* __restrict__ base, const int* __restrict__ ssrc,
    const float* __restrict__ bias, const float* __restrict__ wlin,
    const float* __restrict__ blin, float* __restrict__ out, int N) {
  const int lane = threadIdx.x & 63;
  const int n = blockIdx.x * 4 + (threadIdx.x >> 6);
  if (n >= N) return;
  const int gq = lane >> 4;
  const int l = lane & 15;
  const int b0 = base[n], b1 = base[n + 1];

  int e = b0;
  int p0 = e + gq, p1 = e + 4 + gq;
  int i0 = ssrc[p0], i1 = ssrc[p1];
  i0 = (p0 < b1) ? i0 : N;
  i1 = (p1 < b1) ? i1 : N;
  v8hf r0 = *(const v8hf*)(g + (size_t)i0 * NFEAT + l * 8);
  v8hf r1 = *(const v8hf*)(g + (size_t)i1 * NFEAT + l * 8);
  int e2 = e + 8;
  int j0 = N, j1 = N;
  if (e2 < b1) {
    int q0 = e2 + gq, q1 = e2 + 4 + gq;
    j0 = ssrc[q0]; j1 = ssrc[q1];
    j0 = (q0 < b1) ? j0 : N;
    j1 = (q1 < b1) ? j1 : N;
  }

  float acc[8] = {};
  while (true) {
    bool more = (e2 < b1);
    v8hf s0, s1;
    if (more) {
      s0 = *(const v8hf*)(g + (size_t)j0 * NFEAT + l * 8);
      s1 = *(const v8hf*)(g + (size_t)j1 * NFEAT + l * 8);
    }
    int e3 = e2 + 8;
    int c0 = N, c1 = N;
    if (e3 < b1) {
      int q0 = e3 + gq, q1 = e3 + 4 + gq;
      c0 = ssrc[q0]; c1 = ssrc[q1];
      c0 = (q0 < b1) ? c0 : N;
      c1 = (q1 < b1) ? c1 : N;
    }
    #pragma unroll
    for (int j = 0; j < 8; j++) acc[j] += (float)r0[j] + (float)r1[j];
    if (!more) break;
    r0 = s0; r1 = s1;
    j0 = c0; j1 = c1;
    e2 = e3;
  }

  #pragma unroll
  for (int j = 0; j < 8; j++) {
    acc[j] += __shfl_xor(acc[j], 16, 64);
    acc[j] += __shfl_xor(acc[j], 32, 64);
  }
  float dvn = dinv[n];
  const float* bp = bias + l * 8;
  const float* wp = wlin + l * 8;
  float4 bb0 = *(const float4*)(bp);
  float4 bb1 = *(const float4*)(bp + 4);
  float4 wl0 = *(const float4*)(wp);
  float4 wl1 = *(const float4*)(wp + 4);
  float bv[8] = {bb0.x, bb0.y, bb0.z, bb0.w, bb1.x, bb1.y, bb1.z, bb1.w};
  float wv[8] = {wl0.x, wl0.y, wl0.z, wl0.w, wl1.x, wl1.y, wl1.z, wl1.w};
  float pv = 0.f;
  #pragma unroll
  for (int j = 0; j < 8; j++)
    pv += fmaxf(acc[j] * dvn + bv[j], 0.f) * wv[j];
  pv += __shfl_xor(pv, 1, 64);
  pv += __shfl_xor(pv, 2, 64);
  pv += __shfl_xor(pv, 4, 64);
  pv += __shfl_xor(pv, 8, 64);
  if (lane == 0) out[n] = pv + blin[0];
}

extern "C" void kernel_launch(void* const* d_in, const int* in_sizes, int n_in,
                              void* d_out, int out_size, void* d_ws, size_t ws_size,
                              hipStream_t stream) {
  const float* x    = (const float*)d_in[0];
  const int*   ei   = (const int*)d_in[1];
  const float* W1   = (const float*)d_in[2];
  const float* b1   = (const float*)d_in[3];
  const float* W2   = (const float*)d_in[4];
  const float* b2   = (const float*)d_in[5];
  const float* Wlin = (const float*)d_in[6];
  const float* blin = (const float*)d_in[7];
  const int N = in_sizes[0] / NFEAT;
  const int E = in_sizes[1] / 2;
  const int* src = ei;
  const int* dst = ei + E;
  const int Etot = E + N;   // real edges + self edges

  // workspace layout (4B units)
  int* ws_i = (int*)d_ws;
  size_t off = 0;
  int* deg      = ws_i + off; off += N;
  int* base     = ws_i + off; off += (size_t)N + 1;
  off = (off + 3) & ~(size_t)3;
  int* partials = ws_i + off; off += 128;
  int* ssrc     = ws_i + off; off += Etot + 8;   // +8 slack for tail loads
  float* dinv   = (float*)(ws_i + off); off += N;
  off = (off + 3) & ~(size_t)3;
  _Float16* Wt1 = (_Float16*)(ws_i + off); off += 8192;
  _Float16* Wt2 = (_Float16*)(ws_i + off); off += 8192;
  _Float16* g16 = (_Float16*)(ws_i + off); off += (size_t)(N + 1) * 64;  // +sentinel
  _Float16* hB  = (_Float16*)(ws_i + off); off += (size_t)N * 64;
  int* rank     = (int*)g16;   // Etot ints, consumed by k_scatter before g16 written

  hipMemsetAsync(deg, 0, (size_t)N * sizeof(int), stream);

  const int tpbE = 256;
  const int gE = (Etot + 32768 + tpbE - 1) / tpbE;
  k_deg_rank_w<<<gE, tpbE, 0, stream>>>(dst, deg, rank, E, N, W1, W2, Wt1, Wt2);

  const int nb = (N + 1 + 1023) / 1024;
  k_scan_blocks<<<nb, 1024, 0, stream>>>(deg, base, partials, N);
  k_scan_partials<<<1, 128, 0, stream>>>(partials, nb);
  k_finalize_base<<<((N + 1) + 255) / 256, 256, 0, stream>>>(base, partials, deg, dinv, N);
  k_scatter<<<(Etot + tpbE - 1) / tpbE, tpbE, 0, stream>>>(src, dst, rank, base, ssrc, E, N);

  const int gg = (N + 63) / 64;
  const int ga = (N + 3) / 4;
  // layer 1
  k_gemm_mfma<float><<<gg, 256, 0, stream>>>(x, Wt1, dinv, g16, N);
  k_agg<<<ga, 256, 0, stream>>>(g16, dinv, base, ssrc, b1, hB, N);
  // layer 2 + fused final linear
  k_gemm_mfma<_Float16><<<gg, 256, 0, stream>>>(hB, Wt2, dinv, g16, N);
  k_agg_final<<<ga, 256, 0, stream>>>(g16, dinv, base, ssrc, b2,
                                      Wlin, blin, (float*)d_out, N);
}